// Round 14
// baseline (1651.253 us; speedup 1.0000x reference)
//
#include <hip/hip_runtime.h>
#include <cstddef>
#include <cstdint>

#define BSZ 512
#define SEQ 100

typedef __bf16 bf16_t;
typedef __attribute__((ext_vector_type(8))) __bf16 bf16x8;
typedef __attribute__((ext_vector_type(4))) float f32x4;

__device__ __forceinline__ float sigmoidf_(float v){ return 1.f/(1.f + __expf(-v)); }
__device__ __forceinline__ float siluf_(float v){ return v * sigmoidf_(v); }
__device__ __forceinline__ float softplusf_(float v){ return (v > 20.f) ? v : __logf(1.f + __expf(v)); }

// ---------------------------------------------------------------------------
__global__ __launch_bounds__(256) void cvt_bf16_kernel(
    const float* __restrict__ src, bf16_t* __restrict__ dst, int n)
{
    int i = blockIdx.x*256 + threadIdx.x;
    if (i < n) dst[i] = (bf16_t)src[i];
}

__global__ __launch_bounds__(256) void prep_outw_kernel(
    const float* __restrict__ of, const float* __restrict__ ob, bf16_t* __restrict__ W)
{
    int i = blockIdx.x*256 + threadIdx.x;
    if (i < 512*2048){
        int o = i >> 11, k = i & 2047;
        W[i] = (bf16_t)((k < 1024) ? of[o*1024 + k] : ob[o*1024 + (k - 1024)]);
    }
}

__global__ __launch_bounds__(256) void prep_convw_kernel(
    const float* __restrict__ c1w, const float* __restrict__ c2w,
    bf16_t* __restrict__ W1p, bf16_t* __restrict__ W2p)
{
    int i = blockIdx.x*256 + threadIdx.x;
    if (i < 128*96){
        int o = i / 96, kk = i - o*96, k = kk >> 5, c = kk & 31;
        W1p[i] = (c < 22) ? (bf16_t)c1w[(o*22 + c)*3 + k] : (bf16_t)0.f;
    }
    if (i < 256*384){
        int o = i / 384, kk = i - o*384, k = kk >> 7, c = kk & 127;
        W2p[i] = (bf16_t)c2w[(o*128 + c)*3 + k];
    }
}

// ---------------------------------------------------------------------------
// FE0: id-embed (2 LN) -> comb[...,0:256]; build F0pad; zero F1pad boundary.
// ---------------------------------------------------------------------------
__global__ __launch_bounds__(256) void fe0_kernel(
    const float* __restrict__ x,
    const float* __restrict__ fe_w, const float* __restrict__ fe_b,
    const float* __restrict__ g1, const float* __restrict__ b1,
    const float* __restrict__ g2, const float* __restrict__ b2,
    bf16_t* __restrict__ comb, bf16_t* __restrict__ F0pad, bf16_t* __restrict__ F1pad)
{
    const int b = blockIdx.x;
    const int t = threadIdx.x;
    const int wv = t >> 6, lane = t & 63;

    float few[4], feb[4], lg1[4], lb1[4], lg2[4], lb2[4];
    #pragma unroll
    for (int q = 0; q < 4; ++q){
        int j = lane + 64*q;
        few[q] = fe_w[j]; feb[q] = fe_b[j];
        lg1[q] = g1[j];  lb1[q] = b1[j];
        lg2[q] = g2[j];  lb2[q] = b2[j];
    }
    for (int l = wv; l < SEQ; l += 4){
        float m = fabsf(x[(size_t)(b*SEQ + l)*23]);
        float e[4];
        float s1 = 0.f, s2 = 0.f;
        #pragma unroll
        for (int q = 0; q < 4; ++q){ e[q] = m*few[q] + feb[q]; s1 += e[q]; s2 += e[q]*e[q]; }
        #pragma unroll
        for (int off = 32; off > 0; off >>= 1){ s1 += __shfl_xor(s1, off); s2 += __shfl_xor(s2, off); }
        float mean = s1 * (1.f/256.f);
        float rstd = rsqrtf(s2*(1.f/256.f) - mean*mean + 1e-5f);
        s1 = 0.f; s2 = 0.f;
        #pragma unroll
        for (int q = 0; q < 4; ++q){
            e[q] = fmaxf((e[q]-mean)*rstd*lg1[q] + lb1[q], 0.f);
            s1 += e[q]; s2 += e[q]*e[q];
        }
        #pragma unroll
        for (int off = 32; off > 0; off >>= 1){ s1 += __shfl_xor(s1, off); s2 += __shfl_xor(s2, off); }
        mean = s1 * (1.f/256.f);
        rstd = rsqrtf(s2*(1.f/256.f) - mean*mean + 1e-5f);
        #pragma unroll
        for (int q = 0; q < 4; ++q){
            float v = fmaxf((e[q]-mean)*rstd*lg2[q] + lb2[q], 0.f);
            comb[(size_t)(b*SEQ + l)*512 + lane + 64*q] = (bf16_t)v;
        }
    }

    for (int idx = t; idx < 102*32; idx += 256){
        int r = idx >> 5, c = idx & 31;
        float v = 0.f;
        if (r >= 1 && r <= SEQ && c < 22) v = x[(size_t)(b*SEQ + r - 1)*23 + 1 + c];
        F0pad[(size_t)(b*102 + r)*32 + c] = (bf16_t)v;
    }
    if (t < 128) F1pad[(size_t)(b*102 + 0)*128 + t] = (bf16_t)0.f;
    else F1pad[(size_t)(b*102 + 101)*128 + (t - 128)] = (bf16_t)0.f;
}

// ---------------------------------------------------------------------------
// Conv-as-GEMM (z-batched): C[m,n] = relu(sum_k A_z[m*lda + k]*W[n,k] + bias[n])
// ---------------------------------------------------------------------------
__global__ __launch_bounds__(256) void gemm_conv_kernel(
    const bf16_t* __restrict__ Abase, int lda, int Az,
    const bf16_t* __restrict__ W, int K, int N,
    const float* __restrict__ bias,
    bf16_t* __restrict__ Cbase, int ldc, int Cb, int coff, int noff, int Mtot)
{
    __shared__ bf16_t As[128*32];
    __shared__ bf16_t Ws[128*32];
    const bf16_t* A = Abase + (size_t)blockIdx.z * Az;
    const int t = threadIdx.x;
    const int lane = t & 63, w = t >> 6;
    const int n0 = blockIdx.y * 128;
    const int rsub = lane >> 2, csub = lane & 3;
    const int col = lane & 15, quad = lane >> 4;
    const int wOffM = (w & 1) * 64, wOffN = (w >> 1) * 64;

    f32x4 acc[4][4];
    #pragma unroll
    for (int i = 0; i < 4; ++i)
        #pragma unroll
        for (int j = 0; j < 4; ++j)
            acc[i][j] = (f32x4){0.f, 0.f, 0.f, 0.f};

    for (int k0 = 0; k0 < K; k0 += 32){
        __syncthreads();
        #pragma unroll
        for (int q = 0; q < 2; ++q){
            const int rt = w*32 + q*16 + rsub;
            const int lq = csub ^ ((rt >> 1) & 3);
            int ra = (rt < Mtot) ? rt : (Mtot - 1);
            const bf16_t* ga = A + (size_t)ra*lda + k0 + lq*8;
            __builtin_amdgcn_global_load_lds(
                (const __attribute__((address_space(1))) void*)ga,
                (__attribute__((address_space(3))) void*)&As[(w*32 + q*16)*32], 16, 0, 0);
            const bf16_t* gw = W + (size_t)(n0 + rt)*K + k0 + lq*8;
            __builtin_amdgcn_global_load_lds(
                (const __attribute__((address_space(1))) void*)gw,
                (__attribute__((address_space(3))) void*)&Ws[(w*32 + q*16)*32], 16, 0, 0);
        }
        __syncthreads();

        bf16x8 af[4], bfv[4];
        #pragma unroll
        for (int i = 0; i < 4; ++i){
            const int ra = wOffM + i*16 + col;
            af[i]  = *(const bf16x8*)&As[ra*32 + (quad ^ ((ra >> 1) & 3))*8];
            const int rb = wOffN + i*16 + col;
            bfv[i] = *(const bf16x8*)&Ws[rb*32 + (quad ^ ((rb >> 1) & 3))*8];
        }
        #pragma unroll
        for (int i = 0; i < 4; ++i)
            #pragma unroll
            for (int j = 0; j < 4; ++j)
                acc[i][j] = __builtin_amdgcn_mfma_f32_16x16x32_bf16(af[i], bfv[j], acc[i][j], 0, 0, 0);
    }

    #pragma unroll
    for (int i = 0; i < 4; ++i){
        const int gmb = wOffM + i*16 + quad*4;
        #pragma unroll
        for (int j = 0; j < 4; ++j){
            const int gn = n0 + wOffN + j*16 + col;
            const float bb = bias[gn];
            #pragma unroll
            for (int r = 0; r < 4; ++r){
                const int gm = gmb + r;
                if (gm < Mtot){
                    float v = fmaxf(acc[i][j][r] + bb, 0.f);
                    Cbase[((size_t)blockIdx.z*Cb + coff + gm)*ldc + noff + gn] = (bf16_t)v;
                }
            }
        }
    }
}

// ---------------------------------------------------------------------------
// Merged in-proj GEMM: A=comb (M,512), W=[mf_in; mb_in] (4096,512).
// Double-staged K-loop + LDS-staged coalesced epilogue.
// ---------------------------------------------------------------------------
__global__ __launch_bounds__(256) void gemm_in_kernel(
    const bf16_t* __restrict__ A, int lda, int Mtot,
    const bf16_t* __restrict__ W, int K,
    bf16_t* __restrict__ xy, bf16_t* __restrict__ z)
{
    __shared__ bf16_t smem[128*132];          // 33,792 B; staging uses first 32 KB
    bf16_t* As0 = smem;
    bf16_t* As1 = smem + 4096;
    bf16_t* Ws0 = smem + 8192;
    bf16_t* Ws1 = smem + 12288;
    const int t = threadIdx.x;
    const int lane = t & 63, w = t >> 6;
    const int m0 = blockIdx.x * 128, n0 = blockIdx.y * 128;
    const int rsub = lane >> 2, csub = lane & 3;
    const int col = lane & 15, quad = lane >> 4;
    const int wOffM = (w & 1) * 64, wOffN = (w >> 1) * 64;

    f32x4 acc[4][4];
    #pragma unroll
    for (int i = 0; i < 4; ++i)
        #pragma unroll
        for (int j = 0; j < 4; ++j)
            acc[i][j] = (f32x4){0.f, 0.f, 0.f, 0.f};

    for (int k0 = 0; k0 < K; k0 += 64){
        __syncthreads();
        #pragma unroll
        for (int hh = 0; hh < 2; ++hh){
            bf16_t* Asb = hh ? As1 : As0;
            bf16_t* Wsb = hh ? Ws1 : Ws0;
            #pragma unroll
            for (int q = 0; q < 2; ++q){
                const int rt = w*32 + q*16 + rsub;
                const int lq = csub ^ ((rt >> 1) & 3);
                int ra = m0 + rt; ra = (ra < Mtot) ? ra : (Mtot - 1);
                const bf16_t* ga = A + (size_t)ra*lda + k0 + hh*32 + lq*8;
                __builtin_amdgcn_global_load_lds(
                    (const __attribute__((address_space(1))) void*)ga,
                    (__attribute__((address_space(3))) void*)&Asb[(w*32 + q*16)*32], 16, 0, 0);
                const bf16_t* gw = W + (size_t)(n0 + rt)*K + k0 + hh*32 + lq*8;
                __builtin_amdgcn_global_load_lds(
                    (const __attribute__((address_space(1))) void*)gw,
                    (__attribute__((address_space(3))) void*)&Wsb[(w*32 + q*16)*32], 16, 0, 0);
            }
        }
        __syncthreads();

        #pragma unroll
        for (int hh = 0; hh < 2; ++hh){
            bf16_t* Asb = hh ? As1 : As0;
            bf16_t* Wsb = hh ? Ws1 : Ws0;
            bf16x8 af[4], bfv[4];
            #pragma unroll
            for (int i = 0; i < 4; ++i){
                const int ra = wOffM + i*16 + col;
                af[i]  = *(const bf16x8*)&Asb[ra*32 + (quad ^ ((ra >> 1) & 3))*8];
                const int rb = wOffN + i*16 + col;
                bfv[i] = *(const bf16x8*)&Wsb[rb*32 + (quad ^ ((rb >> 1) & 3))*8];
            }
            #pragma unroll
            for (int i = 0; i < 4; ++i)
                #pragma unroll
                for (int j = 0; j < 4; ++j)
                    acc[i][j] = __builtin_amdgcn_mfma_f32_16x16x32_bf16(af[i], bfv[j], acc[i][j], 0, 0, 0);
        }
    }

    // ---- LDS-staged epilogue ----
    __syncthreads();
    #pragma unroll
    for (int i = 0; i < 4; ++i){
        const int row0 = wOffM + i*16 + quad*4;
        #pragma unroll
        for (int j = 0; j < 4; ++j){
            const int cT = wOffN + j*16 + col;
            #pragma unroll
            for (int r = 0; r < 4; ++r)
                smem[(row0 + r)*132 + cT] = (bf16_t)acc[i][j][r];
        }
    }
    __syncthreads();

    const int half = n0 >> 11, within = n0 & 2047;
    bf16_t* dstBase = ((within < 1024) ? xy : z) + half*1024 + (within & 1023);
    #pragma unroll
    for (int k = 0; k < 8; ++k){
        const int idx = t + k*256;
        const int row = idx >> 4;
        const int ch  = (idx & 15) * 8;
        const int gm = m0 + row;
        if (gm < Mtot)
            *(bf16x8*)&dstBase[(size_t)gm*2048 + ch] = *(const bf16x8*)&smem[row*132 + ch];
    }
}

// ---------------------------------------------------------------------------
// Merged out-proj GEMM: A=[y_f|y_b] (M,2048), W K-concat (512,2048), C fp32.
// Double-staged K-loop.
// ---------------------------------------------------------------------------
__global__ __launch_bounds__(256) void gemm_out_kernel(
    const bf16_t* __restrict__ A, int Mtot,
    const bf16_t* __restrict__ W,
    float* __restrict__ C)
{
    __shared__ bf16_t As[2][128*32];
    __shared__ bf16_t Ws[2][128*32];
    const int t = threadIdx.x;
    const int lane = t & 63, w = t >> 6;
    const int m0 = blockIdx.x * 128, n0 = blockIdx.y * 128;
    const int rsub = lane >> 2, csub = lane & 3;
    const int col = lane & 15, quad = lane >> 4;
    const int wOffM = (w & 1) * 64, wOffN = (w >> 1) * 64;
    const int K = 2048;

    f32x4 acc[4][4];
    #pragma unroll
    for (int i = 0; i < 4; ++i)
        #pragma unroll
        for (int j = 0; j < 4; ++j)
            acc[i][j] = (f32x4){0.f, 0.f, 0.f, 0.f};

    for (int k0 = 0; k0 < K; k0 += 64){
        __syncthreads();
        #pragma unroll
        for (int hh = 0; hh < 2; ++hh){
            #pragma unroll
            for (int q = 0; q < 2; ++q){
                const int rt = w*32 + q*16 + rsub;
                const int lq = csub ^ ((rt >> 1) & 3);
                int ra = m0 + rt; ra = (ra < Mtot) ? ra : (Mtot - 1);
                const bf16_t* ga = A + (size_t)ra*K + k0 + hh*32 + lq*8;
                __builtin_amdgcn_global_load_lds(
                    (const __attribute__((address_space(1))) void*)ga,
                    (__attribute__((address_space(3))) void*)&As[hh][(w*32 + q*16)*32], 16, 0, 0);
                const bf16_t* gw = W + (size_t)(n0 + rt)*K + k0 + hh*32 + lq*8;
                __builtin_amdgcn_global_load_lds(
                    (const __attribute__((address_space(1))) void*)gw,
                    (__attribute__((address_space(3))) void*)&Ws[hh][(w*32 + q*16)*32], 16, 0, 0);
            }
        }
        __syncthreads();

        #pragma unroll
        for (int hh = 0; hh < 2; ++hh){
            bf16x8 af[4], bfv[4];
            #pragma unroll
            for (int i = 0; i < 4; ++i){
                const int ra = wOffM + i*16 + col;
                af[i]  = *(const bf16x8*)&As[hh][ra*32 + (quad ^ ((ra >> 1) & 3))*8];
                const int rb = wOffN + i*16 + col;
                bfv[i] = *(const bf16x8*)&Ws[hh][rb*32 + (quad ^ ((rb >> 1) & 3))*8];
            }
            #pragma unroll
            for (int i = 0; i < 4; ++i)
                #pragma unroll
                for (int j = 0; j < 4; ++j)
                    acc[i][j] = __builtin_amdgcn_mfma_f32_16x16x32_bf16(af[i], bfv[j], acc[i][j], 0, 0, 0);
        }
    }

    #pragma unroll
    for (int i = 0; i < 4; ++i){
        const int gmb = m0 + wOffM + i*16 + quad*4;
        #pragma unroll
        for (int j = 0; j < 4; ++j){
            const int gn = n0 + wOffN + j*16 + col;
            #pragma unroll
            for (int r = 0; r < 4; ++r){
                const int gm = gmb + r;
                if (gm < Mtot)
                    C[(size_t)gm*512 + gn] = acc[i][j][r];
            }
        }
    }
}

// ---------------------------------------------------------------------------
// Merged x-proj GEMM with FUSED dt projection.
// y=0 fwd (N=64, xdb cols 0-63), y=1 bwd (N=48, xdb cols 64-111).
// After the main tile, local cols 0-31 (= dtin for both halves) are written
// to LDS as a swizzled 128x32 bf16 A-operand; 8 MFMA n-tiles against the
// bf16 dt_w (1024x32, K=32 = one mfma per frag) produce
// dtb[m, half*1024 + d] = softplus(dtin·dt_w[d] + dt_b[d]).
// ---------------------------------------------------------------------------
__global__ __launch_bounds__(256) void gemm_x_kernel(
    const bf16_t* __restrict__ xy,
    const bf16_t* __restrict__ Wf, const bf16_t* __restrict__ Wb,
    const bf16_t* __restrict__ dWf, const bf16_t* __restrict__ dWb,
    const float* __restrict__ dbf, const float* __restrict__ dbb,
    float* __restrict__ C,            // xdb (M,128)
    bf16_t* __restrict__ dtb)         // (M,2048)
{
    __shared__ bf16_t As[128*32];     // main A staging; later dtin A2 tile
    __shared__ bf16_t Ws[128*32];     // main W staging (rows 0-63); later dt_w tiles
    const int half = blockIdx.y;
    const bf16_t* A = xy + half*1024;
    const bf16_t* W = half ? Wb : Wf;
    const bf16_t* dW = half ? dWb : dWf;
    const float* db = half ? dbb : dbf;
    const int N = half ? 48 : 64;
    const int t = threadIdx.x;
    const int lane = t & 63, w = t >> 6;
    const int m0 = blockIdx.x * 128;
    const int rsub = lane >> 2, csub = lane & 3;
    const int col = lane & 15, quad = lane >> 4;

    f32x4 acc[2][4];
    #pragma unroll
    for (int i = 0; i < 2; ++i)
        #pragma unroll
        for (int j = 0; j < 4; ++j)
            acc[i][j] = (f32x4){0.f, 0.f, 0.f, 0.f};

    for (int k0 = 0; k0 < 1024; k0 += 32){
        __syncthreads();
        #pragma unroll
        for (int q = 0; q < 2; ++q){
            const int rt = q*64 + w*16 + rsub;
            const int lq = csub ^ ((rt >> 1) & 3);
            const bf16_t* ga = A + (size_t)(m0 + rt)*2048 + k0 + lq*8;
            __builtin_amdgcn_global_load_lds(
                (const __attribute__((address_space(1))) void*)ga,
                (__attribute__((address_space(3))) void*)&As[(q*64 + w*16)*32], 16, 0, 0);
        }
        {
            const int rt = w*16 + rsub;
            const int lq = csub ^ ((rt >> 1) & 3);
            int rw = (rt < N) ? rt : (N - 1);
            const bf16_t* gw = W + (size_t)rw*1024 + k0 + lq*8;
            __builtin_amdgcn_global_load_lds(
                (const __attribute__((address_space(1))) void*)gw,
                (__attribute__((address_space(3))) void*)&Ws[(w*16)*32], 16, 0, 0);
        }
        __syncthreads();

        bf16x8 af[2], bfv[4];
        #pragma unroll
        for (int i = 0; i < 2; ++i){
            const int ra = w*32 + i*16 + col;
            af[i]  = *(const bf16x8*)&As[ra*32 + (quad ^ ((ra >> 1) & 3))*8];
        }
        #pragma unroll
        for (int j = 0; j < 4; ++j){
            const int rb = j*16 + col;
            bfv[j] = *(const bf16x8*)&Ws[rb*32 + (quad ^ ((rb >> 1) & 3))*8];
        }
        #pragma unroll
        for (int i = 0; i < 2; ++i)
            #pragma unroll
            for (int j = 0; j < 4; ++j)
                acc[i][j] = __builtin_amdgcn_mfma_f32_16x16x32_bf16(af[i], bfv[j], acc[i][j], 0, 0, 0);
    }

    // ---- xdb store ----
    #pragma unroll
    for (int i = 0; i < 2; ++i){
        const int gmb = m0 + w*32 + i*16 + quad*4;
        #pragma unroll
        for (int j = 0; j < 4; ++j){
            const int gn = j*16 + col;
            if (gn < N){
                #pragma unroll
                for (int r = 0; r < 4; ++r)
                    C[(size_t)(gmb + r)*128 + half*64 + gn] = acc[i][j][r];
            }
        }
    }

    // ---- fused dt: dtin (local cols 0..31) -> LDS A2, then 8 MFMA n-tiles ----
    __syncthreads();                  // main-loop LDS reads complete
    #pragma unroll
    for (int i = 0; i < 2; ++i){
        const int row0 = w*32 + i*16 + quad*4;
        #pragma unroll
        for (int j = 0; j < 2; ++j){
            const int cc = j*16 + col;            // 0..31
            #pragma unroll
            for (int r = 0; r < 4; ++r){
                const int row = row0 + r;
                const int pc = (cc >> 3) ^ ((row >> 1) & 3);
                As[row*32 + pc*8 + (cc & 7)] = (bf16_t)acc[i][j][r];
            }
        }
    }

    const int wOffM = (w & 1)*64, wOffN = (w >> 1)*64;
    for (int n2 = 0; n2 < 8; ++n2){
        __syncthreads();              // dtin writes visible / prior frag reads done
        #pragma unroll
        for (int q = 0; q < 2; ++q){
            const int rt = w*32 + q*16 + rsub;
            const int lq = csub ^ ((rt >> 1) & 3);
            const bf16_t* gw = dW + (size_t)(n2*128 + rt)*32 + lq*8;
            __builtin_amdgcn_global_load_lds(
                (const __attribute__((address_space(1))) void*)gw,
                (__attribute__((address_space(3))) void*)&Ws[(w*32 + q*16)*32], 16, 0, 0);
        }
        __syncthreads();

        bf16x8 af[4], bfv[4];
        #pragma unroll
        for (int i = 0; i < 4; ++i){
            const int ra = wOffM + i*16 + col;
            af[i]  = *(const bf16x8*)&As[ra*32 + (quad ^ ((ra >> 1) & 3))*8];
            const int rb = wOffN + i*16 + col;
            bfv[i] = *(const bf16x8*)&Ws[rb*32 + (quad ^ ((rb >> 1) & 3))*8];
        }
        f32x4 a2[4][4];
        #pragma unroll
        for (int i = 0; i < 4; ++i)
            #pragma unroll
            for (int j = 0; j < 4; ++j)
                a2[i][j] = __builtin_amdgcn_mfma_f32_16x16x32_bf16(
                    af[i], bfv[j], (f32x4){0.f,0.f,0.f,0.f}, 0, 0, 0);

        #pragma unroll
        for (int i = 0; i < 4; ++i){
            const int gmb = m0 + wOffM + i*16 + quad*4;
            #pragma unroll
            for (int j = 0; j < 4; ++j){
                const int gn = n2*128 + wOffN + j*16 + col;   // 0..1023
                const float bb = db[gn];
                #pragma unroll
                for (int r = 0; r < 4; ++r)
                    dtb[(size_t)(gmb + r)*2048 + half*1024 + gn] =
                        (bf16_t)softplusf_(a2[i][j][r] + bb);
            }
        }
    }
}

// ---------------------------------------------------------------------------
// Merged depthwise conv + bias + silu, IN PLACE on xy (M,2048)
// ---------------------------------------------------------------------------
template<int DC, bool REV>
__device__ __forceinline__ void conv_dev(bf16_t* base, const float* wsrc, float bias)
{
    float w[DC];
    #pragma unroll
    for (int k = 0; k < DC; ++k) w[k] = wsrc[k];
    float hist[DC-1];
    #pragma unroll
    for (int k = 0; k < DC-1; ++k) hist[k] = 0.f;
    const int step = REV ? -1 : 1;
    int l = REV ? (SEQ-1) : 0;
    for (int t0 = 0; t0 < SEQ; t0 += 10){
        float v[10];
        #pragma unroll
        for (int i = 0; i < 10; ++i) v[i] = (float)base[(l + step*i)*2048];
        float o[10];
        #pragma unroll
        for (int i = 0; i < 10; ++i){
            float a = bias + w[DC-1]*v[i];
            #pragma unroll
            for (int j = 1; j < DC; ++j) a += w[DC-1-j]*hist[j-1];
            #pragma unroll
            for (int j = DC-2; j >= 1; --j) hist[j] = hist[j-1];
            hist[0] = v[i];
            o[i] = siluf_(a);
        }
        #pragma unroll
        for (int i = 0; i < 10; ++i)
            base[(l + step*i)*2048] = (bf16_t)o[i];
        l += step*10;
    }
}

__global__ __launch_bounds__(256) void conv_silu_kernel(
    bf16_t* __restrict__ xy,
    const float* __restrict__ cwf, const float* __restrict__ cbf,
    const float* __restrict__ cwb, const float* __restrict__ cbb)
{
    const int gid = blockIdx.x*256 + threadIdx.x;   // Bc*2048 threads
    const int b = gid >> 11, d2 = gid & 2047;
    const int half = d2 >> 10, d = d2 & 1023;
    bf16_t* base = xy + (size_t)b*SEQ*2048 + d2;
    if (half == 0) conv_dev<4, false>(base, cwf + d*4, cbf[d]);
    else           conv_dev<2, true >(base, cwb + d*2, cbb[d]);
}

// ---------------------------------------------------------------------------
// Selective scan (fwd/bwd wave-mixed blocks; int32 inner addressing)
// ---------------------------------------------------------------------------
template<int DS, bool REV, bool STRUCT>
__device__ __forceinline__ void scan_core(
    bf16_t* __restrict__ xybase, const bf16_t* __restrict__ zbase,
    const bf16_t* __restrict__ tbase, const float* __restrict__ sx,
    const float* __restrict__ Av, float Dd)
{
    float h[DS];
    #pragma unroll
    for (int s = 0; s < DS; ++s) h[s] = 0.f;
    const int step = REV ? -1 : 1;
    const float A0 = Av[0];
    int l = REV ? (SEQ-1) : 0;

    for (int t0 = 0; t0 < SEQ; t0 += 10){
        float xr[10], zr[10], tr[10];
        #pragma unroll
        for (int i = 0; i < 10; ++i){
            const int li = (l + step*i)*2048;
            xr[i] = (float)xybase[li];
            zr[i] = (float)zbase[li];
            tr[i] = (float)tbase[li];
        }
        #pragma unroll
        for (int i = 0; i < 10; ++i){
            const int li = l + step*i;
            const float4* sxl4 = (const float4*)&sx[li*2*DS];
            const float dtv = tr[i];
            const float dtx = dtv * xr[i];
            float yv = 0.f;
            if (STRUCT){
                const float r = __expf(dtv*A0);
                float rp = r;
                #pragma unroll
                for (int s4 = 0; s4 < DS/4; ++s4){
                    float4 Bv = sxl4[s4];
                    float4 Cv = sxl4[DS/4 + s4];
                    h[s4*4+0] = rp*h[s4*4+0] + dtx*Bv.x; yv += h[s4*4+0]*Cv.x; rp *= r;
                    h[s4*4+1] = rp*h[s4*4+1] + dtx*Bv.y; yv += h[s4*4+1]*Cv.y; rp *= r;
                    h[s4*4+2] = rp*h[s4*4+2] + dtx*Bv.z; yv += h[s4*4+2]*Cv.z; rp *= r;
                    h[s4*4+3] = rp*h[s4*4+3] + dtx*Bv.w; yv += h[s4*4+3]*Cv.w; rp *= r;
                }
            } else {
                #pragma unroll
                for (int s4 = 0; s4 < DS/4; ++s4){
                    float4 Bv = sxl4[s4];
                    float4 Cv = sxl4[DS/4 + s4];
                    h[s4*4+0] = __expf(dtv*Av[s4*4+0])*h[s4*4+0] + dtx*Bv.x; yv += h[s4*4+0]*Cv.x;
                    h[s4*4+1] = __expf(dtv*Av[s4*4+1])*h[s4*4+1] + dtx*Bv.y; yv += h[s4*4+1]*Cv.y;
                    h[s4*4+2] = __expf(dtv*Av[s4*4+2])*h[s4*4+2] + dtx*Bv.z; yv += h[s4*4+2]*Cv.z;
                    h[s4*4+3] = __expf(dtv*Av[s4*4+3])*h[s4*4+3] + dtx*Bv.w; yv += h[s4*4+3]*Cv.w;
                }
            }
            yv += xr[i]*Dd;
            yv *= siluf_(zr[i]);
            xybase[li*2048] = (bf16_t)yv;
        }
        l += step*10;
    }
}

template<int DS, bool REV>
__device__ __forceinline__ void scan_dev(
    bf16_t* __restrict__ xybase, const bf16_t* __restrict__ zbase,
    const bf16_t* __restrict__ tbase, const float* __restrict__ sx,
    const float* __restrict__ Arow, float Dd)
{
    float Av[DS];
    #pragma unroll
    for (int s = 0; s < DS; ++s) Av[s] = -__expf(Arow[s]);
    bool structured = true;
    #pragma unroll
    for (int s = 1; s < DS; ++s)
        structured = structured && (fabsf(Av[s] - (float)(s+1)*Av[0]) <= 1e-4f*(float)(s+1));
    if (structured) scan_core<DS, REV, true >(xybase, zbase, tbase, sx, Av, Dd);
    else            scan_core<DS, REV, false>(xybase, zbase, tbase, sx, Av, Dd);
}

__global__ __launch_bounds__(256) void scan_kernel(
    bf16_t* __restrict__ xy, const bf16_t* __restrict__ z,
    const bf16_t* __restrict__ dtb, const float* __restrict__ xdb, // (M,128)
    const float* __restrict__ Alogf, const float* __restrict__ Dpf,
    const float* __restrict__ Alogb, const float* __restrict__ Dpb)
{
    const int b = blockIdx.x >> 3, s8 = blockIdx.x & 7;
    const int t = threadIdx.x;
    __shared__ float sxF[SEQ*32];    // fwd B/C slab 12.8 KB
    __shared__ float sxB[SEQ*16];    // bwd B/C slab 6.4 KB
    const float4* src = (const float4*)(xdb + (size_t)b*SEQ*128);

    {
        float4* dstF = (float4*)sxF;
        for (int i = t; i < SEQ*8; i += 256){
            int row = i >> 3, c = i & 7;
            dstF[row*8 + c] = src[row*32 + 8 + c];    // fwd B/C: floats 32..63
        }
        float4* dstB = (float4*)sxB;
        for (int i = t; i < SEQ*4; i += 256){
            int row = i >> 2, c = i & 3;
            dstB[row*4 + c] = src[row*32 + 24 + c];   // bwd B/C: floats 96..111
        }
    }
    __syncthreads();

    if (t < 128){
        const int d = s8*128 + t;                     // fwd channel 0..1023
        const size_t off = (size_t)b*SEQ*2048 + d;
        scan_dev<16, false>(xy + off, z + off, dtb + off, sxF, Alogf + d*16, Dpf[d]);
    } else {
        const int d = s8*128 + (t - 128);             // bwd channel 0..1023
        const size_t off = (size_t)b*SEQ*2048 + 1024 + d;
        scan_dev<8, true>(xy + off, z + off, dtb + off, sxB, Alogb + d*8, Dpb[d]);
    }
}

// ---------------------------------------------------------------------------
// Head: max-pool over L, LN(512), fc1(512->128)+relu, fc2(128->4)
// ---------------------------------------------------------------------------
__global__ __launch_bounds__(256) void head_kernel(
    const float* __restrict__ acc,   // (Bc, L, 512)
    const float* __restrict__ ng, const float* __restrict__ nb,
    const float* __restrict__ w1, const float* __restrict__ b1,
    const float* __restrict__ w2, const float* __restrict__ b2,
    float* __restrict__ out)         // (Bc, 4) chunk base
{
    const int b = blockIdx.x, t = threadIdx.x;
    __shared__ float4 sm4[256];
    __shared__ float sp[512];
    __shared__ float sh2[256];
    __shared__ float sh[128];
    __shared__ float red1[4], red2[4];
    const float* base = acc + (size_t)b*SEQ*512;

    {
        const int c4 = t & 127, lh = t >> 7;
        float4 m = make_float4(-3.4e38f, -3.4e38f, -3.4e38f, -3.4e38f);
        for (int l = lh*50; l < lh*50 + 50; ++l){
            float4 v = ((const float4*)(base + (size_t)l*512))[c4];
            m.x = fmaxf(m.x, v.x); m.y = fmaxf(m.y, v.y);
            m.z = fmaxf(m.z, v.z); m.w = fmaxf(m.w, v.w);
        }
        sm4[t] = m;
    }
    __syncthreads();
    if (t < 128){
        float4 a = sm4[t], c = sm4[t + 128];
        ((float4*)sp)[t] = make_float4(fmaxf(a.x,c.x), fmaxf(a.y,c.y),
                                       fmaxf(a.z,c.z), fmaxf(a.w,c.w));
    }
    __syncthreads();

    float s1 = 0.f, s2 = 0.f;
    for (int o = t; o < 512; o += 256){ float v = sp[o]; s1 += v; s2 += v*v; }
    #pragma unroll
    for (int off = 32; off > 0; off >>= 1){ s1 += __shfl_xor(s1, off); s2 += __shfl_xor(s2, off); }
    const int wv = t >> 6, lane = t & 63;
    if (lane == 0){ red1[wv] = s1; red2[wv] = s2; }
    __syncthreads();
    if (t == 0){
        float a = 0.f, c = 0.f;
        for (int i = 0; i < 4; ++i){ a += red1[i]; c += red2[i]; }
        float mean = a * (1.f/512.f);
        float var = c * (1.f/512.f) - mean*mean;
        red1[0] = mean; red2[0] = rsqrtf(var + 1e-5f);
    }
    __syncthreads();
    const float mean = red1[0], rstd = red2[0];
    for (int o = t; o < 512; o += 256) sp[o] = (sp[o]-mean)*rstd*ng[o] + nb[o];
    __syncthreads();

    {
        const int o = t & 127, half = t >> 7;
        const float4* wrow = (const float4*)(w1 + (size_t)o*512 + half*256);
        const float4* sp4 = (const float4*)sp + half*64;
        float s = 0.f;
        #pragma unroll 8
        for (int j = 0; j < 64; ++j){
            float4 a = sp4[j], wq = wrow[j];
            s += a.x*wq.x + a.y*wq.y + a.z*wq.z + a.w*wq.w;
        }
        sh2[t] = s;
    }
    __syncthreads();
    if (t < 128) sh[t] = fmaxf(sh2[t] + sh2[t + 128] + b1[t], 0.f);
    __syncthreads();
    if (t < 4){
        float a = b2[t];
        for (int j = 0; j < 128; ++j) a += sh[j]*w2[t*128 + j];
        out[b*4 + t] = a;
    }
}

// ---------------------------------------------------------------------------
extern "C" void kernel_launch(void* const* d_in, const int* in_sizes, int n_in,
                              void* d_out, int out_size, void* d_ws, size_t ws_size,
                              hipStream_t stream)
{
    (void)in_sizes; (void)n_in; (void)out_size;
    const float* x        = (const float*)d_in[0];
    const float* fe_w     = (const float*)d_in[1];
    const float* fe_b     = (const float*)d_in[2];
    const float* fe_ln_g  = (const float*)d_in[3];
    const float* fe_ln_b  = (const float*)d_in[4];
    const float* emb_ln_g = (const float*)d_in[5];
    const float* emb_ln_b = (const float*)d_in[6];
    const float* conv1_w  = (const float*)d_in[7];
    const float* conv1_b  = (const float*)d_in[8];
    const float* conv2_w  = (const float*)d_in[9];
    const float* conv2_b  = (const float*)d_in[10];
    const float* mf_in_w  = (const float*)d_in[11];
    const float* mf_conv_w= (const float*)d_in[12];
    const float* mf_conv_b= (const float*)d_in[13];
    const float* mf_xproj = (const float*)d_in[14];
    const float* mf_dt_w  = (const float*)d_in[15];
    const float* mf_dt_b  = (const float*)d_in[16];
    const float* mf_Alog  = (const float*)d_in[17];
    const float* mf_D     = (const float*)d_in[18];
    const float* mf_out_w = (const float*)d_in[19];
    const float* mb_in_w  = (const float*)d_in[20];
    const float* mb_conv_w= (const float*)d_in[21];
    const float* mb_conv_b= (const float*)d_in[22];
    const float* mb_xproj = (const float*)d_in[23];
    const float* mb_dt_w  = (const float*)d_in[24];
    const float* mb_dt_b  = (const float*)d_in[25];
    const float* mb_Alog  = (const float*)d_in[26];
    const float* mb_D     = (const float*)d_in[27];
    const float* mb_out_w = (const float*)d_in[28];
    const float* norm_g   = (const float*)d_in[29];
    const float* norm_b   = (const float*)d_in[30];
    const float* fc1_w    = (const float*)d_in[31];
    const float* fc1_b    = (const float*)d_in[32];
    const float* fc2_w    = (const float*)d_in[33];
    const float* fc2_b    = (const float*)d_in[34];
    float* out = (float*)d_out;

    // ---- fixed workspace region ----
    char* p = (char*)d_ws;
    bf16_t* w_in   = (bf16_t*)p; p += (size_t)4096*512*sizeof(bf16_t);   // [mf; mb]
    bf16_t* w_out  = (bf16_t*)p; p += (size_t)512*2048*sizeof(bf16_t);   // K-concat
    bf16_t* w_xpf  = (bf16_t*)p; p += (size_t)64*1024*sizeof(bf16_t);
    bf16_t* w_xpb  = (bf16_t*)p; p += (size_t)48*1024*sizeof(bf16_t);
    bf16_t* w_dtf  = (bf16_t*)p; p += (size_t)1024*32*sizeof(bf16_t);
    bf16_t* w_dtb  = (bf16_t*)p; p += (size_t)1024*32*sizeof(bf16_t);
    bf16_t* W1p    = (bf16_t*)p; p += (size_t)128*96*sizeof(bf16_t);
    bf16_t* W2p    = (bf16_t*)p; p += (size_t)256*384*sizeof(bf16_t);
    bf16_t* comb_all = (bf16_t*)p; p += (size_t)BSZ*SEQ*512*sizeof(bf16_t);
    const size_t fixed_bytes = (size_t)(p - (char*)d_ws);

    // ---- chunk region ----
    const size_t per_b = (size_t)SEQ * (2048*2 + 2048*2 + 2048*2 + 128*4);
    const size_t budget = (ws_size > fixed_bytes) ? (ws_size - fixed_bytes) : 0;
    int Bc = BSZ;
    while (Bc > 64 && (size_t)Bc * per_b > budget) Bc >>= 1;   // Bc in {512,256,128,64}
    const int nch = BSZ / Bc;
    const int M = Bc * SEQ;

    bf16_t* F0pad = (bf16_t*)p;   // aliases chunk region (pre-loop only)
    bf16_t* F1pad = F0pad + (size_t)BSZ*102*32;
    bf16_t* xy   = (bf16_t*)p;               p += (size_t)M*2048*sizeof(bf16_t);
    bf16_t* z    = (bf16_t*)p;               p += (size_t)M*2048*sizeof(bf16_t);
    bf16_t* dtb  = (bf16_t*)p;               p += (size_t)M*2048*sizeof(bf16_t);
    float*  xdb  = (float*)p;
    float*  accb = (float*)dtb;              // alias: dtb dead when out-proj writes

    // ---- weight conversions / rearrange ----
    cvt_bf16_kernel<<<(2048*512+255)/256, 256, 0, stream>>>(mf_in_w, w_in, 2048*512);
    cvt_bf16_kernel<<<(2048*512+255)/256, 256, 0, stream>>>(mb_in_w, w_in + (size_t)2048*512, 2048*512);
    prep_outw_kernel<<<(512*2048+255)/256, 256, 0, stream>>>(mf_out_w, mb_out_w, w_out);
    cvt_bf16_kernel<<<(64*1024+255)/256,  256, 0, stream>>>(mf_xproj, w_xpf, 64*1024);
    cvt_bf16_kernel<<<(48*1024+255)/256,  256, 0, stream>>>(mb_xproj, w_xpb, 48*1024);
    cvt_bf16_kernel<<<(1024*32+255)/256,  256, 0, stream>>>(mf_dt_w, w_dtf, 1024*32);
    cvt_bf16_kernel<<<(1024*32+255)/256,  256, 0, stream>>>(mb_dt_w, w_dtb, 1024*32);
    prep_convw_kernel<<<(256*384+255)/256, 256, 0, stream>>>(conv1_w, conv2_w, W1p, W2p);

    // ---- front-end ----
    fe0_kernel<<<BSZ, 256, 0, stream>>>(x, fe_w, fe_b, fe_ln_g, fe_ln_b,
        emb_ln_g, emb_ln_b, comb_all, F0pad, F1pad);
    gemm_conv_kernel<<<dim3(1, 1, BSZ), 256, 0, stream>>>(
        F0pad, 32, 102*32, W1p, 96, 128, conv1_b, F1pad, 128, 102, 1, 0, SEQ);
    gemm_conv_kernel<<<dim3(1, 2, BSZ), 256, 0, stream>>>(
        F1pad, 128, 102*128, W2p, 384, 256, conv2_b, comb_all, 512, 100, 0, 256, SEQ);

    const int gm128 = M / 128;

    for (int c = 0; c < nch; ++c){
        const size_t b0 = (size_t)c * Bc;
        const bf16_t* comb = comb_all + b0*SEQ*512;

        gemm_in_kernel<<<dim3(gm128, 32), 256, 0, stream>>>(comb, 512, M, w_in, 512, xy, z);
        conv_silu_kernel<<<Bc*2048/256, 256, 0, stream>>>(xy, mf_conv_w, mf_conv_b,
                                                          mb_conv_w, mb_conv_b);
        gemm_x_kernel<<<dim3(gm128, 2), 256, 0, stream>>>(xy, w_xpf, w_xpb,
                                                          w_dtf, w_dtb, mf_dt_b, mb_dt_b,
                                                          xdb, dtb);
        scan_kernel<<<Bc*8, 256, 0, stream>>>(xy, z, dtb, xdb,
                                              mf_Alog, mf_D, mb_Alog, mb_D);
        gemm_out_kernel<<<dim3(gm128, 4), 256, 0, stream>>>(xy, M, w_out, accb);
        head_kernel<<<Bc, 256, 0, stream>>>(accb, norm_g, norm_b, fc1_w, fc1_b,
                                            fc2_w, fc2_b, out + b0*4);
    }
}

// Round 15
// 1524.814 us; speedup vs baseline: 1.0829x; 1.0829x over previous
//
#include <hip/hip_runtime.h>
#include <cstddef>
#include <cstdint>

#define BSZ 512
#define SEQ 100

typedef __bf16 bf16_t;
typedef __attribute__((ext_vector_type(8))) __bf16 bf16x8;
typedef __attribute__((ext_vector_type(4))) float f32x4;

__device__ __forceinline__ float sigmoidf_(float v){ return 1.f/(1.f + __expf(-v)); }
__device__ __forceinline__ float siluf_(float v){ return v * sigmoidf_(v); }
__device__ __forceinline__ float softplusf_(float v){ return (v > 20.f) ? v : __logf(1.f + __expf(v)); }

// ---------------------------------------------------------------------------
__global__ __launch_bounds__(256) void cvt_bf16_kernel(
    const float* __restrict__ src, bf16_t* __restrict__ dst, int n)
{
    int i = blockIdx.x*256 + threadIdx.x;
    if (i < n) dst[i] = (bf16_t)src[i];
}

__global__ __launch_bounds__(256) void prep_outw_kernel(
    const float* __restrict__ of, const float* __restrict__ ob, bf16_t* __restrict__ W)
{
    int i = blockIdx.x*256 + threadIdx.x;
    if (i < 512*2048){
        int o = i >> 11, k = i & 2047;
        W[i] = (bf16_t)((k < 1024) ? of[o*1024 + k] : ob[o*1024 + (k - 1024)]);
    }
}

__global__ __launch_bounds__(256) void prep_convw_kernel(
    const float* __restrict__ c1w, const float* __restrict__ c2w,
    bf16_t* __restrict__ W1p, bf16_t* __restrict__ W2p)
{
    int i = blockIdx.x*256 + threadIdx.x;
    if (i < 128*96){
        int o = i / 96, kk = i - o*96, k = kk >> 5, c = kk & 31;
        W1p[i] = (c < 22) ? (bf16_t)c1w[(o*22 + c)*3 + k] : (bf16_t)0.f;
    }
    if (i < 256*384){
        int o = i / 384, kk = i - o*384, k = kk >> 7, c = kk & 127;
        W2p[i] = (bf16_t)c2w[(o*128 + c)*3 + k];
    }
}

// ---------------------------------------------------------------------------
// FE0: id-embed (2 LN) -> comb[...,0:256]; build F0pad; zero F1pad boundary.
// ---------------------------------------------------------------------------
__global__ __launch_bounds__(256) void fe0_kernel(
    const float* __restrict__ x,
    const float* __restrict__ fe_w, const float* __restrict__ fe_b,
    const float* __restrict__ g1, const float* __restrict__ b1,
    const float* __restrict__ g2, const float* __restrict__ b2,
    bf16_t* __restrict__ comb, bf16_t* __restrict__ F0pad, bf16_t* __restrict__ F1pad)
{
    const int b = blockIdx.x;
    const int t = threadIdx.x;
    const int wv = t >> 6, lane = t & 63;

    float few[4], feb[4], lg1[4], lb1[4], lg2[4], lb2[4];
    #pragma unroll
    for (int q = 0; q < 4; ++q){
        int j = lane + 64*q;
        few[q] = fe_w[j]; feb[q] = fe_b[j];
        lg1[q] = g1[j];  lb1[q] = b1[j];
        lg2[q] = g2[j];  lb2[q] = b2[j];
    }
    for (int l = wv; l < SEQ; l += 4){
        float m = fabsf(x[(size_t)(b*SEQ + l)*23]);
        float e[4];
        float s1 = 0.f, s2 = 0.f;
        #pragma unroll
        for (int q = 0; q < 4; ++q){ e[q] = m*few[q] + feb[q]; s1 += e[q]; s2 += e[q]*e[q]; }
        #pragma unroll
        for (int off = 32; off > 0; off >>= 1){ s1 += __shfl_xor(s1, off); s2 += __shfl_xor(s2, off); }
        float mean = s1 * (1.f/256.f);
        float rstd = rsqrtf(s2*(1.f/256.f) - mean*mean + 1e-5f);
        s1 = 0.f; s2 = 0.f;
        #pragma unroll
        for (int q = 0; q < 4; ++q){
            e[q] = fmaxf((e[q]-mean)*rstd*lg1[q] + lb1[q], 0.f);
            s1 += e[q]; s2 += e[q]*e[q];
        }
        #pragma unroll
        for (int off = 32; off > 0; off >>= 1){ s1 += __shfl_xor(s1, off); s2 += __shfl_xor(s2, off); }
        mean = s1 * (1.f/256.f);
        rstd = rsqrtf(s2*(1.f/256.f) - mean*mean + 1e-5f);
        #pragma unroll
        for (int q = 0; q < 4; ++q){
            float v = fmaxf((e[q]-mean)*rstd*lg2[q] + lb2[q], 0.f);
            comb[(size_t)(b*SEQ + l)*512 + lane + 64*q] = (bf16_t)v;
        }
    }

    for (int idx = t; idx < 102*32; idx += 256){
        int r = idx >> 5, c = idx & 31;
        float v = 0.f;
        if (r >= 1 && r <= SEQ && c < 22) v = x[(size_t)(b*SEQ + r - 1)*23 + 1 + c];
        F0pad[(size_t)(b*102 + r)*32 + c] = (bf16_t)v;
    }
    if (t < 128) F1pad[(size_t)(b*102 + 0)*128 + t] = (bf16_t)0.f;
    else F1pad[(size_t)(b*102 + 101)*128 + (t - 128)] = (bf16_t)0.f;
}

// ---------------------------------------------------------------------------
// Conv-as-GEMM (z-batched): C[m,n] = relu(sum_k A_z[m*lda + k]*W[n,k] + bias[n])
// ---------------------------------------------------------------------------
__global__ __launch_bounds__(256) void gemm_conv_kernel(
    const bf16_t* __restrict__ Abase, int lda, int Az,
    const bf16_t* __restrict__ W, int K, int N,
    const float* __restrict__ bias,
    bf16_t* __restrict__ Cbase, int ldc, int Cb, int coff, int noff, int Mtot)
{
    __shared__ bf16_t As[128*32];
    __shared__ bf16_t Ws[128*32];
    const bf16_t* A = Abase + (size_t)blockIdx.z * Az;
    const int t = threadIdx.x;
    const int lane = t & 63, w = t >> 6;
    const int n0 = blockIdx.y * 128;
    const int rsub = lane >> 2, csub = lane & 3;
    const int col = lane & 15, quad = lane >> 4;
    const int wOffM = (w & 1) * 64, wOffN = (w >> 1) * 64;

    f32x4 acc[4][4];
    #pragma unroll
    for (int i = 0; i < 4; ++i)
        #pragma unroll
        for (int j = 0; j < 4; ++j)
            acc[i][j] = (f32x4){0.f, 0.f, 0.f, 0.f};

    for (int k0 = 0; k0 < K; k0 += 32){
        __syncthreads();
        #pragma unroll
        for (int q = 0; q < 2; ++q){
            const int rt = w*32 + q*16 + rsub;
            const int lq = csub ^ ((rt >> 1) & 3);
            int ra = (rt < Mtot) ? rt : (Mtot - 1);
            const bf16_t* ga = A + (size_t)ra*lda + k0 + lq*8;
            __builtin_amdgcn_global_load_lds(
                (const __attribute__((address_space(1))) void*)ga,
                (__attribute__((address_space(3))) void*)&As[(w*32 + q*16)*32], 16, 0, 0);
            const bf16_t* gw = W + (size_t)(n0 + rt)*K + k0 + lq*8;
            __builtin_amdgcn_global_load_lds(
                (const __attribute__((address_space(1))) void*)gw,
                (__attribute__((address_space(3))) void*)&Ws[(w*32 + q*16)*32], 16, 0, 0);
        }
        __syncthreads();

        bf16x8 af[4], bfv[4];
        #pragma unroll
        for (int i = 0; i < 4; ++i){
            const int ra = wOffM + i*16 + col;
            af[i]  = *(const bf16x8*)&As[ra*32 + (quad ^ ((ra >> 1) & 3))*8];
            const int rb = wOffN + i*16 + col;
            bfv[i] = *(const bf16x8*)&Ws[rb*32 + (quad ^ ((rb >> 1) & 3))*8];
        }
        #pragma unroll
        for (int i = 0; i < 4; ++i)
            #pragma unroll
            for (int j = 0; j < 4; ++j)
                acc[i][j] = __builtin_amdgcn_mfma_f32_16x16x32_bf16(af[i], bfv[j], acc[i][j], 0, 0, 0);
    }

    #pragma unroll
    for (int i = 0; i < 4; ++i){
        const int gmb = wOffM + i*16 + quad*4;
        #pragma unroll
        for (int j = 0; j < 4; ++j){
            const int gn = n0 + wOffN + j*16 + col;
            const float bb = bias[gn];
            #pragma unroll
            for (int r = 0; r < 4; ++r){
                const int gm = gmb + r;
                if (gm < Mtot){
                    float v = fmaxf(acc[i][j][r] + bb, 0.f);
                    Cbase[((size_t)blockIdx.z*Cb + coff + gm)*ldc + noff + gn] = (bf16_t)v;
                }
            }
        }
    }
}

// ---------------------------------------------------------------------------
// Merged in-proj GEMM: A=comb (M,512), W=[mf_in; mb_in] (4096,512).
// Double-staged K-loop + LDS-staged coalesced epilogue.
// ---------------------------------------------------------------------------
__global__ __launch_bounds__(256) void gemm_in_kernel(
    const bf16_t* __restrict__ A, int lda, int Mtot,
    const bf16_t* __restrict__ W, int K,
    bf16_t* __restrict__ xy, bf16_t* __restrict__ z)
{
    __shared__ bf16_t smem[128*132];          // 33,792 B; staging uses first 32 KB
    bf16_t* As0 = smem;
    bf16_t* As1 = smem + 4096;
    bf16_t* Ws0 = smem + 8192;
    bf16_t* Ws1 = smem + 12288;
    const int t = threadIdx.x;
    const int lane = t & 63, w = t >> 6;
    const int m0 = blockIdx.x * 128, n0 = blockIdx.y * 128;
    const int rsub = lane >> 2, csub = lane & 3;
    const int col = lane & 15, quad = lane >> 4;
    const int wOffM = (w & 1) * 64, wOffN = (w >> 1) * 64;

    f32x4 acc[4][4];
    #pragma unroll
    for (int i = 0; i < 4; ++i)
        #pragma unroll
        for (int j = 0; j < 4; ++j)
            acc[i][j] = (f32x4){0.f, 0.f, 0.f, 0.f};

    for (int k0 = 0; k0 < K; k0 += 64){
        __syncthreads();
        #pragma unroll
        for (int hh = 0; hh < 2; ++hh){
            bf16_t* Asb = hh ? As1 : As0;
            bf16_t* Wsb = hh ? Ws1 : Ws0;
            #pragma unroll
            for (int q = 0; q < 2; ++q){
                const int rt = w*32 + q*16 + rsub;
                const int lq = csub ^ ((rt >> 1) & 3);
                int ra = m0 + rt; ra = (ra < Mtot) ? ra : (Mtot - 1);
                const bf16_t* ga = A + (size_t)ra*lda + k0 + hh*32 + lq*8;
                __builtin_amdgcn_global_load_lds(
                    (const __attribute__((address_space(1))) void*)ga,
                    (__attribute__((address_space(3))) void*)&Asb[(w*32 + q*16)*32], 16, 0, 0);
                const bf16_t* gw = W + (size_t)(n0 + rt)*K + k0 + hh*32 + lq*8;
                __builtin_amdgcn_global_load_lds(
                    (const __attribute__((address_space(1))) void*)gw,
                    (__attribute__((address_space(3))) void*)&Wsb[(w*32 + q*16)*32], 16, 0, 0);
            }
        }
        __syncthreads();

        #pragma unroll
        for (int hh = 0; hh < 2; ++hh){
            bf16_t* Asb = hh ? As1 : As0;
            bf16_t* Wsb = hh ? Ws1 : Ws0;
            bf16x8 af[4], bfv[4];
            #pragma unroll
            for (int i = 0; i < 4; ++i){
                const int ra = wOffM + i*16 + col;
                af[i]  = *(const bf16x8*)&Asb[ra*32 + (quad ^ ((ra >> 1) & 3))*8];
                const int rb = wOffN + i*16 + col;
                bfv[i] = *(const bf16x8*)&Wsb[rb*32 + (quad ^ ((rb >> 1) & 3))*8];
            }
            #pragma unroll
            for (int i = 0; i < 4; ++i)
                #pragma unroll
                for (int j = 0; j < 4; ++j)
                    acc[i][j] = __builtin_amdgcn_mfma_f32_16x16x32_bf16(af[i], bfv[j], acc[i][j], 0, 0, 0);
        }
    }

    // ---- LDS-staged epilogue ----
    __syncthreads();
    #pragma unroll
    for (int i = 0; i < 4; ++i){
        const int row0 = wOffM + i*16 + quad*4;
        #pragma unroll
        for (int j = 0; j < 4; ++j){
            const int cT = wOffN + j*16 + col;
            #pragma unroll
            for (int r = 0; r < 4; ++r)
                smem[(row0 + r)*132 + cT] = (bf16_t)acc[i][j][r];
        }
    }
    __syncthreads();

    const int half = n0 >> 11, within = n0 & 2047;
    bf16_t* dstBase = ((within < 1024) ? xy : z) + half*1024 + (within & 1023);
    #pragma unroll
    for (int k = 0; k < 8; ++k){
        const int idx = t + k*256;
        const int row = idx >> 4;
        const int ch  = (idx & 15) * 8;
        const int gm = m0 + row;
        if (gm < Mtot)
            *(bf16x8*)&dstBase[(size_t)gm*2048 + ch] = *(const bf16x8*)&smem[row*132 + ch];
    }
}

// ---------------------------------------------------------------------------
// Merged out-proj GEMM: A=[y_f|y_b] (M,2048), W K-concat (512,2048), C fp32.
// Double-staged K-loop.
// ---------------------------------------------------------------------------
__global__ __launch_bounds__(256) void gemm_out_kernel(
    const bf16_t* __restrict__ A, int Mtot,
    const bf16_t* __restrict__ W,
    float* __restrict__ C)
{
    __shared__ bf16_t As[2][128*32];
    __shared__ bf16_t Ws[2][128*32];
    const int t = threadIdx.x;
    const int lane = t & 63, w = t >> 6;
    const int m0 = blockIdx.x * 128, n0 = blockIdx.y * 128;
    const int rsub = lane >> 2, csub = lane & 3;
    const int col = lane & 15, quad = lane >> 4;
    const int wOffM = (w & 1) * 64, wOffN = (w >> 1) * 64;
    const int K = 2048;

    f32x4 acc[4][4];
    #pragma unroll
    for (int i = 0; i < 4; ++i)
        #pragma unroll
        for (int j = 0; j < 4; ++j)
            acc[i][j] = (f32x4){0.f, 0.f, 0.f, 0.f};

    for (int k0 = 0; k0 < K; k0 += 64){
        __syncthreads();
        #pragma unroll
        for (int hh = 0; hh < 2; ++hh){
            #pragma unroll
            for (int q = 0; q < 2; ++q){
                const int rt = w*32 + q*16 + rsub;
                const int lq = csub ^ ((rt >> 1) & 3);
                int ra = m0 + rt; ra = (ra < Mtot) ? ra : (Mtot - 1);
                const bf16_t* ga = A + (size_t)ra*K + k0 + hh*32 + lq*8;
                __builtin_amdgcn_global_load_lds(
                    (const __attribute__((address_space(1))) void*)ga,
                    (__attribute__((address_space(3))) void*)&As[hh][(w*32 + q*16)*32], 16, 0, 0);
                const bf16_t* gw = W + (size_t)(n0 + rt)*K + k0 + hh*32 + lq*8;
                __builtin_amdgcn_global_load_lds(
                    (const __attribute__((address_space(1))) void*)gw,
                    (__attribute__((address_space(3))) void*)&Ws[hh][(w*32 + q*16)*32], 16, 0, 0);
            }
        }
        __syncthreads();

        #pragma unroll
        for (int hh = 0; hh < 2; ++hh){
            bf16x8 af[4], bfv[4];
            #pragma unroll
            for (int i = 0; i < 4; ++i){
                const int ra = wOffM + i*16 + col;
                af[i]  = *(const bf16x8*)&As[hh][ra*32 + (quad ^ ((ra >> 1) & 3))*8];
                const int rb = wOffN + i*16 + col;
                bfv[i] = *(const bf16x8*)&Ws[hh][rb*32 + (quad ^ ((rb >> 1) & 3))*8];
            }
            #pragma unroll
            for (int i = 0; i < 4; ++i)
                #pragma unroll
                for (int j = 0; j < 4; ++j)
                    acc[i][j] = __builtin_amdgcn_mfma_f32_16x16x32_bf16(af[i], bfv[j], acc[i][j], 0, 0, 0);
        }
    }

    #pragma unroll
    for (int i = 0; i < 4; ++i){
        const int gmb = m0 + wOffM + i*16 + quad*4;
        #pragma unroll
        for (int j = 0; j < 4; ++j){
            const int gn = n0 + wOffN + j*16 + col;
            #pragma unroll
            for (int r = 0; r < 4; ++r){
                const int gm = gmb + r;
                if (gm < Mtot)
                    C[(size_t)gm*512 + gn] = acc[i][j][r];
            }
        }
    }
}

// ---------------------------------------------------------------------------
// Merged x-proj GEMM: y=0 fwd (N=64, C cols 0-63), y=1 bwd (N=48, cols 64-111).
// ---------------------------------------------------------------------------
__global__ __launch_bounds__(256) void gemm_x_kernel(
    const bf16_t* __restrict__ xy,
    const bf16_t* __restrict__ Wf, const bf16_t* __restrict__ Wb,
    float* __restrict__ C)
{
    __shared__ bf16_t As[128*32];
    __shared__ bf16_t Ws[64*32];
    const int half = blockIdx.y;
    const bf16_t* A = xy + half*1024;
    const bf16_t* W = half ? Wb : Wf;
    const int N = half ? 48 : 64;
    const int t = threadIdx.x;
    const int lane = t & 63, w = t >> 6;
    const int m0 = blockIdx.x * 128;
    const int rsub = lane >> 2, csub = lane & 3;
    const int col = lane & 15, quad = lane >> 4;

    f32x4 acc[2][4];
    #pragma unroll
    for (int i = 0; i < 2; ++i)
        #pragma unroll
        for (int j = 0; j < 4; ++j)
            acc[i][j] = (f32x4){0.f, 0.f, 0.f, 0.f};

    for (int k0 = 0; k0 < 1024; k0 += 32){
        __syncthreads();
        #pragma unroll
        for (int q = 0; q < 2; ++q){
            const int rt = q*64 + w*16 + rsub;
            const int lq = csub ^ ((rt >> 1) & 3);
            const bf16_t* ga = A + (size_t)(m0 + rt)*2048 + k0 + lq*8;
            __builtin_amdgcn_global_load_lds(
                (const __attribute__((address_space(1))) void*)ga,
                (__attribute__((address_space(3))) void*)&As[(q*64 + w*16)*32], 16, 0, 0);
        }
        {
            const int rt = w*16 + rsub;
            const int lq = csub ^ ((rt >> 1) & 3);
            int rw = (rt < N) ? rt : (N - 1);
            const bf16_t* gw = W + (size_t)rw*1024 + k0 + lq*8;
            __builtin_amdgcn_global_load_lds(
                (const __attribute__((address_space(1))) void*)gw,
                (__attribute__((address_space(3))) void*)&Ws[(w*16)*32], 16, 0, 0);
        }
        __syncthreads();

        bf16x8 af[2], bfv[4];
        #pragma unroll
        for (int i = 0; i < 2; ++i){
            const int ra = w*32 + i*16 + col;
            af[i]  = *(const bf16x8*)&As[ra*32 + (quad ^ ((ra >> 1) & 3))*8];
        }
        #pragma unroll
        for (int j = 0; j < 4; ++j){
            const int rb = j*16 + col;
            bfv[j] = *(const bf16x8*)&Ws[rb*32 + (quad ^ ((rb >> 1) & 3))*8];
        }
        #pragma unroll
        for (int i = 0; i < 2; ++i)
            #pragma unroll
            for (int j = 0; j < 4; ++j)
                acc[i][j] = __builtin_amdgcn_mfma_f32_16x16x32_bf16(af[i], bfv[j], acc[i][j], 0, 0, 0);
    }

    #pragma unroll
    for (int i = 0; i < 2; ++i){
        const int gmb = m0 + w*32 + i*16 + quad*4;
        #pragma unroll
        for (int j = 0; j < 4; ++j){
            const int gn = j*16 + col;
            if (gn < N){
                #pragma unroll
                for (int r = 0; r < 4; ++r)
                    C[(size_t)(gmb + r)*128 + half*64 + gn] = acc[i][j][r];
            }
        }
    }
}

// ---------------------------------------------------------------------------
// Merged dt projection: grid (M/16, 16); blockIdx.y<8 -> fwd, else bwd.
// ---------------------------------------------------------------------------
__global__ __launch_bounds__(256) void dt_kernel(
    const float* __restrict__ xdb,   // (M, 128)
    const float* __restrict__ dtwf, const float* __restrict__ dtbf,
    const float* __restrict__ dtwb, const float* __restrict__ dtbb,
    bf16_t* __restrict__ dtb)        // (M, 2048)
{
    const int half = blockIdx.y >> 3;
    const int d = (blockIdx.y & 7)*128 + (threadIdx.x & 127);
    const int mslot = threadIdx.x >> 7;
    const int m0 = blockIdx.x * 16;
    __shared__ float sd[16*32];
    for (int i = threadIdx.x; i < 16*32; i += 256){
        int r = i >> 5, c = i & 31;
        sd[i] = xdb[(size_t)(m0 + r)*128 + half*64 + c];
    }
    const float* dw = half ? dtwb : dtwf;
    float w[32];
    #pragma unroll
    for (int r = 0; r < 32; ++r) w[r] = dw[d*32 + r];
    const float db = half ? dtbb[d] : dtbf[d];
    __syncthreads();
    #pragma unroll
    for (int i = 0; i < 8; ++i){
        const int row = mslot + i*2;
        const float* rp = &sd[row*32];
        float a = db;
        #pragma unroll
        for (int r = 0; r < 32; ++r) a += w[r]*rp[r];
        dtb[(size_t)(m0 + row)*2048 + half*1024 + d] = (bf16_t)softplusf_(a);
    }
}

// ---------------------------------------------------------------------------
// Merged depthwise conv + bias + silu, IN PLACE on xy (M,2048)
// ---------------------------------------------------------------------------
template<int DC, bool REV>
__device__ __forceinline__ void conv_dev(bf16_t* base, const float* wsrc, float bias)
{
    float w[DC];
    #pragma unroll
    for (int k = 0; k < DC; ++k) w[k] = wsrc[k];
    float hist[DC-1];
    #pragma unroll
    for (int k = 0; k < DC-1; ++k) hist[k] = 0.f;
    const int step = REV ? -1 : 1;
    int l = REV ? (SEQ-1) : 0;
    for (int t0 = 0; t0 < SEQ; t0 += 10){
        float v[10];
        #pragma unroll
        for (int i = 0; i < 10; ++i) v[i] = (float)base[(size_t)(l + step*i)*2048];
        float o[10];
        #pragma unroll
        for (int i = 0; i < 10; ++i){
            float a = bias + w[DC-1]*v[i];
            #pragma unroll
            for (int j = 1; j < DC; ++j) a += w[DC-1-j]*hist[j-1];
            #pragma unroll
            for (int j = DC-2; j >= 1; --j) hist[j] = hist[j-1];
            hist[0] = v[i];
            o[i] = siluf_(a);
        }
        #pragma unroll
        for (int i = 0; i < 10; ++i)
            base[(size_t)(l + step*i)*2048] = (bf16_t)o[i];
        l += step*10;
    }
}

__global__ __launch_bounds__(256) void conv_silu_kernel(
    bf16_t* __restrict__ xy,
    const float* __restrict__ cwf, const float* __restrict__ cbf,
    const float* __restrict__ cwb, const float* __restrict__ cbb)
{
    const int gid = blockIdx.x*256 + threadIdx.x;   // Bc*2048 threads
    const int b = gid >> 11, d2 = gid & 2047;
    const int half = d2 >> 10, d = d2 & 1023;
    bf16_t* base = xy + (size_t)b*SEQ*2048 + d2;
    if (half == 0) conv_dev<4, false>(base, cwf + d*4, cbf[d]);
    else           conv_dev<2, true >(base, cwb + d*2, cbb[d]);
}

// ---------------------------------------------------------------------------
// Selective scan (fwd/bwd wave-mixed blocks)
// ---------------------------------------------------------------------------
template<int DS, bool REV, bool STRUCT>
__device__ __forceinline__ void scan_core(
    bf16_t* __restrict__ xybase, const bf16_t* __restrict__ zbase,
    const bf16_t* __restrict__ tbase, const float* __restrict__ sx,
    const float* __restrict__ Av, float Dd)
{
    float h[DS];
    #pragma unroll
    for (int s = 0; s < DS; ++s) h[s] = 0.f;
    const int step = REV ? -1 : 1;
    const float A0 = Av[0];
    int l = REV ? (SEQ-1) : 0;

    for (int t0 = 0; t0 < SEQ; t0 += 10){
        float xr[10], zr[10], tr[10];
        #pragma unroll
        for (int i = 0; i < 10; ++i){
            const size_t li = (size_t)(l + step*i);
            xr[i] = (float)xybase[li*2048];
            zr[i] = (float)zbase[li*2048];
            tr[i] = (float)tbase[li*2048];
        }
        #pragma unroll
        for (int i = 0; i < 10; ++i){
            const int li = l + step*i;
            const float4* sxl4 = (const float4*)&sx[li*2*DS];
            const float dtv = tr[i];
            const float dtx = dtv * xr[i];
            float yv = 0.f;
            if (STRUCT){
                const float r = __expf(dtv*A0);
                float rp = r;
                #pragma unroll
                for (int s4 = 0; s4 < DS/4; ++s4){
                    float4 Bv = sxl4[s4];
                    float4 Cv = sxl4[DS/4 + s4];
                    h[s4*4+0] = rp*h[s4*4+0] + dtx*Bv.x; yv += h[s4*4+0]*Cv.x; rp *= r;
                    h[s4*4+1] = rp*h[s4*4+1] + dtx*Bv.y; yv += h[s4*4+1]*Cv.y; rp *= r;
                    h[s4*4+2] = rp*h[s4*4+2] + dtx*Bv.z; yv += h[s4*4+2]*Cv.z; rp *= r;
                    h[s4*4+3] = rp*h[s4*4+3] + dtx*Bv.w; yv += h[s4*4+3]*Cv.w; rp *= r;
                }
            } else {
                #pragma unroll
                for (int s4 = 0; s4 < DS/4; ++s4){
                    float4 Bv = sxl4[s4];
                    float4 Cv = sxl4[DS/4 + s4];
                    h[s4*4+0] = __expf(dtv*Av[s4*4+0])*h[s4*4+0] + dtx*Bv.x; yv += h[s4*4+0]*Cv.x;
                    h[s4*4+1] = __expf(dtv*Av[s4*4+1])*h[s4*4+1] + dtx*Bv.y; yv += h[s4*4+1]*Cv.y;
                    h[s4*4+2] = __expf(dtv*Av[s4*4+2])*h[s4*4+2] + dtx*Bv.z; yv += h[s4*4+2]*Cv.z;
                    h[s4*4+3] = __expf(dtv*Av[s4*4+3])*h[s4*4+3] + dtx*Bv.w; yv += h[s4*4+3]*Cv.w;
                }
            }
            yv += xr[i]*Dd;
            yv *= siluf_(zr[i]);
            xybase[(size_t)li*2048] = (bf16_t)yv;
        }
        l += step*10;
    }
}

template<int DS, bool REV>
__device__ __forceinline__ void scan_dev(
    bf16_t* __restrict__ xybase, const bf16_t* __restrict__ zbase,
    const bf16_t* __restrict__ tbase, const float* __restrict__ sx,
    const float* __restrict__ Arow, float Dd)
{
    float Av[DS];
    #pragma unroll
    for (int s = 0; s < DS; ++s) Av[s] = -__expf(Arow[s]);
    bool structured = true;
    #pragma unroll
    for (int s = 1; s < DS; ++s)
        structured = structured && (fabsf(Av[s] - (float)(s+1)*Av[0]) <= 1e-4f*(float)(s+1));
    if (structured) scan_core<DS, REV, true >(xybase, zbase, tbase, sx, Av, Dd);
    else            scan_core<DS, REV, false>(xybase, zbase, tbase, sx, Av, Dd);
}

__global__ __launch_bounds__(256) void scan_kernel(
    bf16_t* __restrict__ xy, const bf16_t* __restrict__ z,
    const bf16_t* __restrict__ dtb, const float* __restrict__ xdb, // (M,128)
    const float* __restrict__ Alogf, const float* __restrict__ Dpf,
    const float* __restrict__ Alogb, const float* __restrict__ Dpb)
{
    const int b = blockIdx.x >> 3, s8 = blockIdx.x & 7;
    const int t = threadIdx.x;
    __shared__ float sxF[SEQ*32];    // fwd B/C slab 12.8 KB
    __shared__ float sxB[SEQ*16];    // bwd B/C slab 6.4 KB
    const float4* src = (const float4*)(xdb + (size_t)b*SEQ*128);

    {
        float4* dstF = (float4*)sxF;
        for (int i = t; i < SEQ*8; i += 256){
            int row = i >> 3, c = i & 7;
            dstF[row*8 + c] = src[row*32 + 8 + c];    // fwd B/C: floats 32..63
        }
        float4* dstB = (float4*)sxB;
        for (int i = t; i < SEQ*4; i += 256){
            int row = i >> 2, c = i & 3;
            dstB[row*4 + c] = src[row*32 + 24 + c];   // bwd B/C: floats 96..111
        }
    }
    __syncthreads();

    if (t < 128){
        const int d = s8*128 + t;                     // fwd channel 0..1023
        const size_t off = (size_t)b*SEQ*2048 + d;
        scan_dev<16, false>(xy + off, z + off, dtb + off, sxF, Alogf + d*16, Dpf[d]);
    } else {
        const int d = s8*128 + (t - 128);             // bwd channel 0..1023
        const size_t off = (size_t)b*SEQ*2048 + 1024 + d;
        scan_dev<8, true>(xy + off, z + off, dtb + off, sxB, Alogb + d*8, Dpb[d]);
    }
}

// ---------------------------------------------------------------------------
// Head: max-pool over L, LN(512), fc1(512->128)+relu, fc2(128->4)
// ---------------------------------------------------------------------------
__global__ __launch_bounds__(256) void head_kernel(
    const float* __restrict__ acc,   // (Bc, L, 512)
    const float* __restrict__ ng, const float* __restrict__ nb,
    const float* __restrict__ w1, const float* __restrict__ b1,
    const float* __restrict__ w2, const float* __restrict__ b2,
    float* __restrict__ out)         // (Bc, 4) chunk base
{
    const int b = blockIdx.x, t = threadIdx.x;
    __shared__ float4 sm4[256];
    __shared__ float sp[512];
    __shared__ float sh2[256];
    __shared__ float sh[128];
    __shared__ float red1[4], red2[4];
    const float* base = acc + (size_t)b*SEQ*512;

    {
        const int c4 = t & 127, lh = t >> 7;
        float4 m = make_float4(-3.4e38f, -3.4e38f, -3.4e38f, -3.4e38f);
        for (int l = lh*50; l < lh*50 + 50; ++l){
            float4 v = ((const float4*)(base + (size_t)l*512))[c4];
            m.x = fmaxf(m.x, v.x); m.y = fmaxf(m.y, v.y);
            m.z = fmaxf(m.z, v.z); m.w = fmaxf(m.w, v.w);
        }
        sm4[t] = m;
    }
    __syncthreads();
    if (t < 128){
        float4 a = sm4[t], c = sm4[t + 128];
        ((float4*)sp)[t] = make_float4(fmaxf(a.x,c.x), fmaxf(a.y,c.y),
                                       fmaxf(a.z,c.z), fmaxf(a.w,c.w));
    }
    __syncthreads();

    float s1 = 0.f, s2 = 0.f;
    for (int o = t; o < 512; o += 256){ float v = sp[o]; s1 += v; s2 += v*v; }
    #pragma unroll
    for (int off = 32; off > 0; off >>= 1){ s1 += __shfl_xor(s1, off); s2 += __shfl_xor(s2, off); }
    const int wv = t >> 6, lane = t & 63;
    if (lane == 0){ red1[wv] = s1; red2[wv] = s2; }
    __syncthreads();
    if (t == 0){
        float a = 0.f, c = 0.f;
        for (int i = 0; i < 4; ++i){ a += red1[i]; c += red2[i]; }
        float mean = a * (1.f/512.f);
        float var = c * (1.f/512.f) - mean*mean;
        red1[0] = mean; red2[0] = rsqrtf(var + 1e-5f);
    }
    __syncthreads();
    const float mean = red1[0], rstd = red2[0];
    for (int o = t; o < 512; o += 256) sp[o] = (sp[o]-mean)*rstd*ng[o] + nb[o];
    __syncthreads();

    {
        const int o = t & 127, half = t >> 7;
        const float4* wrow = (const float4*)(w1 + (size_t)o*512 + half*256);
        const float4* sp4 = (const float4*)sp + half*64;
        float s = 0.f;
        #pragma unroll 8
        for (int j = 0; j < 64; ++j){
            float4 a = sp4[j], wq = wrow[j];
            s += a.x*wq.x + a.y*wq.y + a.z*wq.z + a.w*wq.w;
        }
        sh2[t] = s;
    }
    __syncthreads();
    if (t < 128) sh[t] = fmaxf(sh2[t] + sh2[t + 128] + b1[t], 0.f);
    __syncthreads();
    if (t < 4){
        float a = b2[t];
        for (int j = 0; j < 128; ++j) a += sh[j]*w2[t*128 + j];
        out[b*4 + t] = a;
    }
}

// ---------------------------------------------------------------------------
extern "C" void kernel_launch(void* const* d_in, const int* in_sizes, int n_in,
                              void* d_out, int out_size, void* d_ws, size_t ws_size,
                              hipStream_t stream)
{
    (void)in_sizes; (void)n_in; (void)out_size;
    const float* x        = (const float*)d_in[0];
    const float* fe_w     = (const float*)d_in[1];
    const float* fe_b     = (const float*)d_in[2];
    const float* fe_ln_g  = (const float*)d_in[3];
    const float* fe_ln_b  = (const float*)d_in[4];
    const float* emb_ln_g = (const float*)d_in[5];
    const float* emb_ln_b = (const float*)d_in[6];
    const float* conv1_w  = (const float*)d_in[7];
    const float* conv1_b  = (const float*)d_in[8];
    const float* conv2_w  = (const float*)d_in[9];
    const float* conv2_b  = (const float*)d_in[10];
    const float* mf_in_w  = (const float*)d_in[11];
    const float* mf_conv_w= (const float*)d_in[12];
    const float* mf_conv_b= (const float*)d_in[13];
    const float* mf_xproj = (const float*)d_in[14];
    const float* mf_dt_w  = (const float*)d_in[15];
    const float* mf_dt_b  = (const float*)d_in[16];
    const float* mf_Alog  = (const float*)d_in[17];
    const float* mf_D     = (const float*)d_in[18];
    const float* mf_out_w = (const float*)d_in[19];
    const float* mb_in_w  = (const float*)d_in[20];
    const float* mb_conv_w= (const float*)d_in[21];
    const float* mb_conv_b= (const float*)d_in[22];
    const float* mb_xproj = (const float*)d_in[23];
    const float* mb_dt_w  = (const float*)d_in[24];
    const float* mb_dt_b  = (const float*)d_in[25];
    const float* mb_Alog  = (const float*)d_in[26];
    const float* mb_D     = (const float*)d_in[27];
    const float* mb_out_w = (const float*)d_in[28];
    const float* norm_g   = (const float*)d_in[29];
    const float* norm_b   = (const float*)d_in[30];
    const float* fc1_w    = (const float*)d_in[31];
    const float* fc1_b    = (const float*)d_in[32];
    const float* fc2_w    = (const float*)d_in[33];
    const float* fc2_b    = (const float*)d_in[34];
    float* out = (float*)d_out;

    // ---- fixed workspace region ----
    char* p = (char*)d_ws;
    bf16_t* w_in   = (bf16_t*)p; p += (size_t)4096*512*sizeof(bf16_t);   // [mf; mb]
    bf16_t* w_out  = (bf16_t*)p; p += (size_t)512*2048*sizeof(bf16_t);   // K-concat
    bf16_t* w_xpf  = (bf16_t*)p; p += (size_t)64*1024*sizeof(bf16_t);
    bf16_t* w_xpb  = (bf16_t*)p; p += (size_t)48*1024*sizeof(bf16_t);
    bf16_t* W1p    = (bf16_t*)p; p += (size_t)128*96*sizeof(bf16_t);
    bf16_t* W2p    = (bf16_t*)p; p += (size_t)256*384*sizeof(bf16_t);
    bf16_t* comb_all = (bf16_t*)p; p += (size_t)BSZ*SEQ*512*sizeof(bf16_t);
    const size_t fixed_bytes = (size_t)(p - (char*)d_ws);

    // ---- chunk region ----
    const size_t per_b = (size_t)SEQ * (2048*2 + 2048*2 + 2048*2 + 128*4);
    const size_t budget = (ws_size > fixed_bytes) ? (ws_size - fixed_bytes) : 0;
    int Bc = BSZ;
    while (Bc > 64 && (size_t)Bc * per_b > budget) Bc >>= 1;   // Bc in {512,256,128,64}
    const int nch = BSZ / Bc;
    const int M = Bc * SEQ;

    bf16_t* F0pad = (bf16_t*)p;   // aliases chunk region (pre-loop only)
    bf16_t* F1pad = F0pad + (size_t)BSZ*102*32;
    bf16_t* xy   = (bf16_t*)p;               p += (size_t)M*2048*sizeof(bf16_t);
    bf16_t* z    = (bf16_t*)p;               p += (size_t)M*2048*sizeof(bf16_t);
    bf16_t* dtb  = (bf16_t*)p;               p += (size_t)M*2048*sizeof(bf16_t);
    float*  xdb  = (float*)p;
    float*  accb = (float*)dtb;              // alias: dtb dead when out-proj writes

    // ---- weight conversions / rearrange ----
    cvt_bf16_kernel<<<(2048*512+255)/256, 256, 0, stream>>>(mf_in_w, w_in, 2048*512);
    cvt_bf16_kernel<<<(2048*512+255)/256, 256, 0, stream>>>(mb_in_w, w_in + (size_t)2048*512, 2048*512);
    prep_outw_kernel<<<(512*2048+255)/256, 256, 0, stream>>>(mf_out_w, mb_out_w, w_out);
    cvt_bf16_kernel<<<(64*1024+255)/256,  256, 0, stream>>>(mf_xproj, w_xpf, 64*1024);
    cvt_bf16_kernel<<<(48*1024+255)/256,  256, 0, stream>>>(mb_xproj, w_xpb, 48*1024);
    prep_convw_kernel<<<(256*384+255)/256, 256, 0, stream>>>(conv1_w, conv2_w, W1p, W2p);

    // ---- front-end ----
    fe0_kernel<<<BSZ, 256, 0, stream>>>(x, fe_w, fe_b, fe_ln_g, fe_ln_b,
        emb_ln_g, emb_ln_b, comb_all, F0pad, F1pad);
    gemm_conv_kernel<<<dim3(1, 1, BSZ), 256, 0, stream>>>(
        F0pad, 32, 102*32, W1p, 96, 128, conv1_b, F1pad, 128, 102, 1, 0, SEQ);
    gemm_conv_kernel<<<dim3(1, 2, BSZ), 256, 0, stream>>>(
        F1pad, 128, 102*128, W2p, 384, 256, conv2_b, comb_all, 512, 100, 0, 256, SEQ);

    const int gm128 = M / 128;

    for (int c = 0; c < nch; ++c){
        const size_t b0 = (size_t)c * Bc;
        const bf16_t* comb = comb_all + b0*SEQ*512;

        gemm_in_kernel<<<dim3(gm128, 32), 256, 0, stream>>>(comb, 512, M, w_in, 512, xy, z);
        conv_silu_kernel<<<Bc*2048/256, 256, 0, stream>>>(xy, mf_conv_w, mf_conv_b,
                                                          mb_conv_w, mb_conv_b);
        gemm_x_kernel<<<dim3(gm128, 2), 256, 0, stream>>>(xy, w_xpf, w_xpb, xdb);
        dt_kernel<<<dim3(M/16, 16), 256, 0, stream>>>(xdb, mf_dt_w, mf_dt_b,
                                                      mb_dt_w, mb_dt_b, dtb);
        scan_kernel<<<Bc*8, 256, 0, stream>>>(xy, z, dtb, xdb,
                                              mf_Alog, mf_D, mb_Alog, mb_D);
        gemm_out_kernel<<<dim3(gm128, 4), 256, 0, stream>>>(xy, M, w_out, accb);
        head_kernel<<<Bc, 256, 0, stream>>>(accb, norm_g, norm_b, fc1_w, fc1_b,
                                            fc2_w, fc2_b, out + b0*4);
    }
}